// Round 7
// baseline (299.049 us; speedup 1.0000x reference)
//
#include <hip/hip_runtime.h>
#include <hip/hip_fp16.h>

#define B 32
#define R 2048
#define C 32
#define O 32
#define IN 16

typedef _Float16 hf2 __attribute__((ext_vector_type(2)));

// votes_h layout: per (b,c) slice of 65536 halfs; word index rp*32+o holds
// half2(v[2rp][o], v[2rp+1][o]).

// ---------------------------------------------------------------------------
// K1: block = (16-row chunk, c), 512 threads:
//   bq = t>>7 (bb chunk of 8), rp_l = (t>>4)&7, op = t&15 (o-pair).
// Thread computes rows (r, r+1) x o-pair for 8 b's via v_dot2_f32_f16.
// 16 KB LDS, launch_bounds(512,6) -> 3 blocks/CU (24 waves, 75% occ).
// ---------------------------------------------------------------------------
__global__ __launch_bounds__(512, 6) void votes_kernel(
    const float* __restrict__ x,     // [B][R][IN] fp32
    const float* __restrict__ vote,  // [R][C][O][IN] fp32
    __half* __restrict__ votes_h)
{
  const int t = threadIdx.x;
  const int c = blockIdx.y;
  const int bq = t >> 7;           // 0..3
  const int rp_l = (t >> 4) & 7;   // 0..7
  const int op = t & 15;           // o-pair
  const int r0 = blockIdx.x * 16;
  const int r = r0 + 2 * rp_l;
  const int rpg = blockIdx.x * 8 + rp_l;  // global row-pair

  __shared__ unsigned int x_lds[32 * 16 * 8];  // [bb][rl][8 words], 16 KB

  // ---- stage x fp32 -> fp16 (2048 float4, 4 per thread, coalesced) ----
#pragma unroll
  for (int k = 0; k < 4; ++k) {
    int j = t + k * 512;
    int bb = j >> 6;
    int rr = (j >> 2) & 15;
    int ic = j & 3;
    float4 v = *reinterpret_cast<const float4*>(
        x + ((size_t)bb * R + r0 + rr) * IN + ic * 4);
    __half2 h01 = __float22half2_rn(make_float2(v.x, v.y));
    __half2 h23 = __float22half2_rn(make_float2(v.z, v.w));
    int w = (bb * 16 + rr) * 8 + 2 * ic;
    x_lds[w] = __builtin_bit_cast(unsigned int, h01);
    x_lds[w + 1] = __builtin_bit_cast(unsigned int, h23);
  }

  // ---- load + convert 4 vote rows (rows r,r+1 x o=2op,2op+1) ----
  unsigned int wh[4][8];
#pragma unroll
  for (int p = 0; p < 2; ++p) {
#pragma unroll
    for (int q = 0; q < 2; ++q) {
      const float4* vp = reinterpret_cast<const float4*>(
          vote + (((size_t)(r + p) * C + c) * O + 2 * op + q) * IN);
#pragma unroll
      for (int k = 0; k < 4; ++k) {
        float4 f = vp[k];
        __half2 a = __float22half2_rn(make_float2(f.x, f.y));
        __half2 d = __float22half2_rn(make_float2(f.z, f.w));
        wh[p * 2 + q][2 * k] = __builtin_bit_cast(unsigned int, a);
        wh[p * 2 + q][2 * k + 1] = __builtin_bit_cast(unsigned int, d);
      }
    }
  }
  __syncthreads();

  __half* ob = votes_h + (size_t)c * 65536 + (size_t)rpg * 64 + op * 4;

#pragma unroll
  for (int jj = 0; jj < 8; ++jj) {
    const int bb = bq * 8 + jj;
    const uint4* xr = reinterpret_cast<const uint4*>(
        &x_lds[(bb * 16 + 2 * rp_l) * 8]);
    uint4 xa = xr[0], xb = xr[1];  // row r   (8 half2)
    uint4 xc = xr[2], xd = xr[3];  // row r+1 (8 half2)
    unsigned int x0[8] = {xa.x, xa.y, xa.z, xa.w, xb.x, xb.y, xb.z, xb.w};
    unsigned int x1[8] = {xc.x, xc.y, xc.z, xc.w, xd.x, xd.y, xd.z, xd.w};
    float a00 = 0.f, a01 = 0.f, a10 = 0.f, a11 = 0.f;
#pragma unroll
    for (int k = 0; k < 8; ++k) {
      hf2 xv0 = __builtin_bit_cast(hf2, x0[k]);
      hf2 xv1 = __builtin_bit_cast(hf2, x1[k]);
      a00 = __builtin_amdgcn_fdot2(__builtin_bit_cast(hf2, wh[0][k]), xv0, a00, false);
      a01 = __builtin_amdgcn_fdot2(__builtin_bit_cast(hf2, wh[1][k]), xv0, a01, false);
      a10 = __builtin_amdgcn_fdot2(__builtin_bit_cast(hf2, wh[2][k]), xv1, a10, false);
      a11 = __builtin_amdgcn_fdot2(__builtin_bit_cast(hf2, wh[3][k]), xv1, a11, false);
    }
    __half2 w0 = __float22half2_rn(make_float2(a00, a10));
    __half2 w1 = __float22half2_rn(make_float2(a01, a11));
    uint2 pk;
    pk.x = __builtin_bit_cast(unsigned int, w0);
    pk.y = __builtin_bit_cast(unsigned int, w1);
    *reinterpret_cast<uint2*>(ob + (size_t)bb * C * 65536) = pk;
  }
}

// ---------------------------------------------------------------------------
// K2: one block per (b,c), 1024 threads. vmix[rp][o] at word rp*34+o.
// iter-0 S is folded into the staging loop (uniform chairman): each thread's
// staged chunks share a constant o-quad (t&7), so 4 column partials
// accumulate in registers during load; shuffle+LDS finish. No exp/e2/S-pass
// for iter 0.
// ---------------------------------------------------------------------------
__global__ __launch_bounds__(1024, 4) void routing_kernel(
    const __half* __restrict__ votes_h,
    float* __restrict__ out)  // [B][C][O]
{
  const int b = blockIdx.x >> 5;
  const int c = blockIdx.x & 31;
  const int t = threadIdx.x;
  const int lane = t & 63;
  const int wave = t >> 6;  // 0..15
  const int g = t >> 5;     // 0..31
  const int o = t & 31;

  __shared__ unsigned int vmix[1024 * 34];  // 139264 B
  __shared__ float2 e2[1024];               // 8 KB
  __shared__ float red[32][33];             // 4224 B
  __shared__ float s0red[16][8][4];         // 2 KB (iter-0 partials)
  __shared__ float vdf[32];
  __shared__ float scal_z[16];

  // ---- stage votes slice (128 KB) + iter-0 column partials ----
  const uint4* src = reinterpret_cast<const uint4*>(
      votes_h + ((size_t)b * C + c) * 65536);
  const int o4 = t & 7;  // constant o-quad for all 8 staged chunks
  float s4[4] = {0.f, 0.f, 0.f, 0.f};
#pragma unroll
  for (int k = 0; k < 8; ++k) {
    int j = t + k * 1024;
    uint4 v = src[j];
    int rp = j >> 3;
    unsigned int* dst = &vmix[rp * 34 + 4 * o4];
    uint2 a; a.x = v.x; a.y = v.y;
    uint2 d; d.x = v.z; d.y = v.w;
    *reinterpret_cast<uint2*>(dst) = a;
    *reinterpret_cast<uint2*>(dst + 2) = d;
    __half2 h0 = __builtin_bit_cast(__half2, v.x);
    __half2 h1 = __builtin_bit_cast(__half2, v.y);
    __half2 h2 = __builtin_bit_cast(__half2, v.z);
    __half2 h3 = __builtin_bit_cast(__half2, v.w);
    s4[0] += __low2float(h0) + __high2float(h0);
    s4[1] += __low2float(h1) + __high2float(h1);
    s4[2] += __low2float(h2) + __high2float(h2);
    s4[3] += __low2float(h3) + __high2float(h3);
  }
  // reduce over the 8 lanes sharing o4 within the wave (bits 3,4,5 of lane)
#pragma unroll
  for (int mask = 8; mask <= 32; mask <<= 1) {
#pragma unroll
    for (int m = 0; m < 4; ++m) s4[m] += __shfl_xor(s4[m], mask);
  }
  if (lane < 8) {
#pragma unroll
    for (int m = 0; m < 4; ++m) s0red[wave][lane][m] = s4[m];
  }
  __syncthreads();

  float a0 = 0.0f, a1 = 0.0f;

  for (int iter = 0; iter < 3; ++iter) {
    float Zinv;
    if (iter == 0) {
      Zinv = 1.0f / 2048.0f;
    } else {
      float e0 = __expf(a0), e1 = __expf(a1);
      float z = e0 + e1;
#pragma unroll
      for (int mask = 32; mask; mask >>= 1) z += __shfl_xor(z, mask);
      if (lane == 0) scal_z[wave] = z;
      e2[t] = make_float2(e0, e1);
      __syncthreads();
      float Z = 0.0f;
#pragma unroll
      for (int w = 0; w < 16; ++w) Z += scal_z[w];
      Zinv = 1.0f / Z;

      // ---- S partials: thread (g,o) sums 32 row-pairs ----
      float s = 0.0f;
      const unsigned int* vb = &vmix[(size_t)g * 32 * 34 + o];
      const float2* eb = &e2[g * 32];
#pragma unroll
      for (int j = 0; j < 32; ++j) {
        __half2 vv = __builtin_bit_cast(__half2, vb[j * 34]);
        float2 ee = eb[j];
        s += ee.x * __low2float(vv) + ee.y * __high2float(vv);
      }
      red[o][g] = s;
      __syncthreads();
    }

    // ---- wave 0: finish S, squash, publish verdict ----
    if (t < 32) {
      float S = 0.0f;
      if (iter == 0) {
#pragma unroll
        for (int w = 0; w < 16; ++w) S += s0red[w][t >> 2][t & 3];
      } else {
#pragma unroll
        for (int gg = 0; gg < 32; ++gg) S += red[t][gg];
      }
      float summary = S * Zinv;
      float sq = summary * summary;
#pragma unroll
      for (int mask = 16; mask; mask >>= 1) sq += __shfl_xor(sq, mask);
      float scale = sq / ((1.0f + sq) * sqrtf(sq + 1e-8f));
      float vd = summary * scale;
      vdf[t] = vd;
      if (iter == 2) out[((size_t)b * C + c) * O + t] = vd;
    }
    __syncthreads();

    // ---- agreement update (dead on last iter) ----
    if (iter < 2) {
      float u0 = 0.0f, u1 = 0.0f;
      const unsigned int* vb = &vmix[(size_t)t * 34];
#pragma unroll
      for (int q = 0; q < 16; ++q) {
        uint2 vv = *reinterpret_cast<const uint2*>(vb + 2 * q);
        __half2 va = __builtin_bit_cast(__half2, vv.x);   // o = 2q
        __half2 vbh = __builtin_bit_cast(__half2, vv.y);  // o = 2q+1
        float vda = vdf[2 * q], vdb = vdf[2 * q + 1];
        u0 += __low2float(va) * vda + __low2float(vbh) * vdb;
        u1 += __high2float(va) * vda + __high2float(vbh) * vdb;
      }
      a0 += u0;
      a1 += u1;
      __syncthreads();
    }
  }
}

extern "C" void kernel_launch(void* const* d_in, const int* in_sizes, int n_in,
                              void* d_out, int out_size, void* d_ws, size_t ws_size,
                              hipStream_t stream) {
  const float* x = (const float*)d_in[0];     // [32][2048][16]
  const float* vote = (const float*)d_in[1];  // [2048][32][32][16]
  float* out = (float*)d_out;                 // [32][32][32]
  __half* votes_h = (__half*)d_ws;            // 128 MB interleaved

  votes_kernel<<<dim3(R / 16, C), 512, 0, stream>>>(x, vote, votes_h);
  routing_kernel<<<dim3(B * C), 1024, 0, stream>>>(votes_h, out);
}